// Round 11
// baseline (515.343 us; speedup 1.0000x reference)
//
#include <hip/hip_runtime.h>
#include <hip/hip_bf16.h>
#include <stdint.h>

// ---------------------------------------------------------------------------
// Decoder (teacher-forced, state never advances):
//   gates = x @ W_ih^T + (h0 @ W_hh^T + b_ih + b_hh)  (broadcast over t)
//   i,f,g,o = split(gates); c' = sig(f)*c0 + sig(i)*tanh(g); h' = sig(o)*tanh(c')
//   out = h' @ fc_w^T + fc_b
// Sizes: B=64, T=1024, D=513, H=512, 4H=2048.  M = B*T = 65536.
// R10: B-direct-to-register. Weights are L2-resident; pre-pack them
//     FRAGMENT-ORDERED in global ((ns,kc) -> 64 lanes x 16B contiguous) and
//     load each wave's 4 B-frags straight to VGPRs via coalesced
//     global_load_dwordx4 (vector-mem pipe), double-buffered one K-tile
//     ahead. Only A goes through LDS (3 x 16KB triple buffer): per-CU LDS
//     traffic drops ~2x -> MFMA pipe becomes the longest pole.
//     One counted wait per round: vmcnt(6)+lgkmcnt(0) (tail 4/0), then
//     sched_barrier + setprio'd 16-MFMA cluster + barrier. Geometry = R6:
//     256x128 tile, 8 waves (4Mx2N), BK=32, 2 blocks/CU, XCD swizzle,
//     fragment-ordered identity LDS (0 conflicts), gate-interleaved W
//     (lane-local LSTM epilogue), full unroll.
// ---------------------------------------------------------------------------

typedef __bf16 bf16x8 __attribute__((ext_vector_type(8)));
typedef float f32x4 __attribute__((ext_vector_type(4)));

#define MFMA_BF16 __builtin_amdgcn_mfma_f32_16x16x32_bf16

__device__ __forceinline__ void gld16(const void* gptr, void* lptr) {
  __builtin_amdgcn_global_load_lds(
      (const __attribute__((address_space(1))) void*)gptr,
      (__attribute__((address_space(3))) void*)lptr, 16, 0, 0);
}

__device__ __forceinline__ float fsigm(float x) {
  x = fminf(fmaxf(x, -30.f), 30.f);
  return __frcp_rn(1.f + __expf(-x));
}
__device__ __forceinline__ float ftanh(float x) {
  x = fminf(fmaxf(x, -15.f), 15.f);
  const float e = __expf(2.f * x);
  return (e - 1.f) * __frcp_rn(e + 1.f);
}

// --------------------------- pack fp32 -> bf16 (A matrix) -------------------
__global__ void pack_bf16_kernel(const float* __restrict__ in,
                                 __bf16* __restrict__ out,
                                 int rows_in, int kin, int kout) {
  const int r = blockIdx.x;
  const bool rv = r < rows_in;
  for (int c = threadIdx.x * 2; c < kout; c += 512) {
    float v0 = (rv && c < kin) ? in[(size_t)r * kin + c] : 0.f;
    float v1 = (rv && c + 1 < kin) ? in[(size_t)r * kin + c + 1] : 0.f;
    union { __bf16 h[2]; uint32_t u; } p;
    p.h[0] = (__bf16)v0;
    p.h[1] = (__bf16)v1;
    *(uint32_t*)&out[(size_t)r * kout + c] = p.u;
  }
}

// pack W_ih gate-interleaved AND fragment-ordered:
// packed row p -> gate (p>>4)&3, h (p>>6)*16+(p&15); ns=p>>4, pr=p&15.
// frag cell (ns, kc) is 1KB: lane l=(kq<<4)|pr holds row pr, k kc*32+kq*8..+8.
__global__ void pack_wfrag_kernel(const float* __restrict__ Wih,
                                  __bf16* __restrict__ dst) {
  const int p = blockIdx.x;  // 0..2047
  const int g = (p >> 4) & 3;
  const int h = ((p >> 6) << 4) + (p & 15);
  const float* src = Wih + (size_t)(g * 512 + h) * 513;
  const int ns = p >> 4, pr = p & 15;
  const int c8 = threadIdx.x;  // 8-elem chunk, 0..67 used
  if (c8 < 68) {
    union { __bf16 v[8]; uint4 u; } pk;
#pragma unroll
    for (int j = 0; j < 8; ++j) {
      const int c = c8 * 8 + j;
      pk.v[j] = (__bf16)((c < 513) ? src[c] : 0.f);
    }
    *(uint4*)((char*)dst + (((ns * 17) + (c8 >> 2)) << 10) +
              (((((c8 & 3) << 4)) | pr) << 4)) = pk.u;
  }
}

// pack fc_w fragment-ordered: rows n 0..639 (>=513 zero), K=512 (16 chunks).
__global__ void pack_fcwfrag_kernel(const float* __restrict__ W,
                                    __bf16* __restrict__ dst) {
  const int n = blockIdx.x;  // 0..639
  const int ns = n >> 4, nr = n & 15;
  const float* src = W + (size_t)n * 512;
  const int c8 = threadIdx.x;  // 0..63
  union { __bf16 v[8]; uint4 u; } pk;
#pragma unroll
  for (int j = 0; j < 8; ++j)
    pk.v[j] = (__bf16)((n < 513) ? src[c8 * 8 + j] : 0.f);
  *(uint4*)((char*)dst + (((ns * 16) + (c8 >> 2)) << 10) +
            (((((c8 & 3) << 4)) | nr) << 4)) = pk.u;
}

// --------------------------- hbias ------------------------------------------
__global__ void hbias_kernel(const float* __restrict__ h0,
                             const float* __restrict__ Whh,
                             const float* __restrict__ bih,
                             const float* __restrict__ bhh,
                             float* __restrict__ hbias) {
  const int t = threadIdx.x, w = t >> 6, l = t & 63;
  const int b = blockIdx.x >> 9;
  const int g = ((blockIdx.x & 511) << 2) | w;
  const float* hr = h0 + b * 512;
  const float* wr = Whh + (size_t)g * 512;
  float s = 0.f;
#pragma unroll
  for (int h = 0; h < 512; h += 64) s = fmaf(hr[h + l], wr[h + l], s);
#pragma unroll
  for (int off = 32; off; off >>= 1) s += __shfl_down(s, off);
  if (l == 0) hbias[b * 2048 + g] = s + bih[g] + bhh[g];
}

// --------------------------- B-direct GEMM core -----------------------------
// Block tile 256x128, BK=32, 8 waves (4M x 2N), per-wave 64x64 (acc[4][4]).
// A: LDS 3 buffers x 16KB, fragment-ordered identity (0 conflicts),
//    2 gld16/thread/K-tile, staged 2 tiles ahead.
// B: fragment-ordered global (L2-resident), 4 global_load_dwordx4/wave/tile
//    direct to regs, double-buffered (set kt&1), loaded 1 tile ahead.
// Round kt: ds_read A(kt) | LOADB(kt+1) | STAGEA(kt+2) |
//           vmcnt(N)+lgkmcnt(0) (N=4*(kt+1<NKT)+2*(kt+2<NKT)) |
//           sched_barrier | setprio 16xMFMA | barrier.
// vmcnt(6) drains B(kt) and A(kt+1) (both older than the 6 newest) -> MFMA
// operands ready and next round's LDS reads safe. 3-buffer rotation race-free:
// reads of buf b drain (lgkmcnt 0) before the barrier 2 rounds prior to its
// restage.
template <int NKT, int KSTR, int KC>
__device__ __forceinline__ void gemm_core(
    const __bf16* __restrict__ A, const __bf16* __restrict__ Bf,
    size_t m0, int nsbase, char* lds, f32x4 (&acc)[4][4],
    int wid, int l, int wm, int wc) {
  const int lr = l & 15, lq = l >> 4;
  const __bf16* ag = A + (m0 + wid * 16 + lr) * KSTR + lq * 8;
  const __bf16* ag2 = ag + (size_t)128 * KSTR;
  const int sdA = wid << 10;           // A subtile wid (+8192: wid+8)
  const int ra = (wm << 12) + l * 16;  // A read: subtile wm*4+mi
  // B fragment base: subtile nsbase+wc*4+ni, cell (ns,kc) at (ns*KC+kc)*1KB
  const __bf16* bsrc = Bf + (((size_t)(nsbase + wc * 4) * KC) << 9) + l * 8;

#define STAGEA(T)                                      \
  {                                                    \
    char* wb_ = lds + ((T) % 3) * 16384;               \
    gld16(ag + (T) * 32, wb_ + sdA);                   \
    gld16(ag2 + (T) * 32, wb_ + sdA + 8192);           \
  }
#define LOADB(T)                                       \
  {                                                    \
    _Pragma("unroll")                                  \
    for (int ni_ = 0; ni_ < 4; ++ni_)                  \
      breg[(T) & 1][ni_] =                             \
          *(const bf16x8*)(bsrc + (ni_ * KC + (T)) * 512); \
  }

  bf16x8 breg[2][4];
  // prologue: A tiles 0,1 -> bufs 0,1; B tile 0 -> set 0
  STAGEA(0);
  STAGEA(1);
  LOADB(0);
  asm volatile("s_waitcnt vmcnt(6)" ::: "memory");  // A(0) landed
  __builtin_amdgcn_s_barrier();

#pragma unroll
  for (int kt = 0; kt < NKT; ++kt) {
    const char* rbase = lds + (kt % 3) * 16384;
    bf16x8 af[4];
#pragma unroll
    for (int i = 0; i < 4; ++i)
      af[i] = *(const bf16x8*)(rbase + ra + i * 1024);
    if (kt + 1 < NKT) LOADB(kt + 1);
    if (kt + 2 < NKT) STAGEA(kt + 2);
    // counted wait: leave only B(kt+1)[4] + A-stage(kt+2)[2] outstanding
    if (kt + 2 < NKT) {
      asm volatile("s_waitcnt vmcnt(6) lgkmcnt(0)" ::: "memory");
    } else if (kt + 1 < NKT) {
      asm volatile("s_waitcnt vmcnt(4) lgkmcnt(0)" ::: "memory");
    } else {
      asm volatile("s_waitcnt vmcnt(0) lgkmcnt(0)" ::: "memory");
    }
    __builtin_amdgcn_sched_barrier(0);
    __builtin_amdgcn_s_setprio(1);
#pragma unroll
    for (int mi = 0; mi < 4; ++mi)
#pragma unroll
      for (int ni = 0; ni < 4; ++ni)
        acc[mi][ni] = MFMA_BF16(af[mi], breg[kt & 1][ni], acc[mi][ni], 0, 0, 0);
    __builtin_amdgcn_s_setprio(0);
    asm volatile("" ::: "memory");
    __builtin_amdgcn_s_barrier();
  }
#undef STAGEA
#undef LOADB
}

// --------------------------- GEMM1 + LSTM cell ------------------------------
// A = xbf [65536 x 544], B = wpkf fragment-ordered [128 ns x 17 kc x 1KB].
// grid 4096 = 256 m-tiles x 16 n-tiles.
__global__ __launch_bounds__(512, 4) void gemm1_kernel(
    const __bf16* __restrict__ xbf, const __bf16* __restrict__ wpkf,
    const float* __restrict__ hbias, const float* __restrict__ c0,
    __bf16* __restrict__ hnew) {
  const int t = threadIdx.x, wid = t >> 6, l = t & 63;
  const int wm = wid >> 1, wc = wid & 1;
  const int bid = blockIdx.x;
  const int swz = (bid & 7) * 512 + (bid >> 3);  // XCD-contiguous
  const size_t m0 = (size_t)(swz >> 4) << 8;
  const int n0 = (swz & 15) << 7;

  __shared__ __align__(16) char lds[49152];

  f32x4 acc[4][4];
#pragma unroll
  for (int mi = 0; mi < 4; ++mi)
#pragma unroll
    for (int ni = 0; ni < 4; ++ni) acc[mi][ni] = (f32x4){0.f, 0.f, 0.f, 0.f};

  gemm_core<17, 544, 17>(xbf, wpkf, m0, n0 >> 4, lds, acc, wid, l, wm, wc);

  // lane's packed col p = n0 + wc*64 + ni*16 + lr -> gate = ni,
  // h = (n0/64 + wc)*16 + lr. All 4 gates lane-local.
  const int lr = l & 15, lq = l >> 4;
  const int hcol = (((n0 >> 6) + wc) << 4) + lr;
  const int b = (int)(m0 >> 10);
  const float hb0 = hbias[b * 2048 + hcol];
  const float hb1 = hbias[b * 2048 + 512 + hcol];
  const float hb2 = hbias[b * 2048 + 1024 + hcol];
  const float hb3 = hbias[b * 2048 + 1536 + hcol];
  const float c0v = c0[b * 512 + hcol];
#pragma unroll
  for (int mi = 0; mi < 4; ++mi) {
#pragma unroll
    for (int r = 0; r < 4; ++r) {
      const size_t m = m0 + wm * 64 + mi * 16 + lq * 4 + r;
      const float gi = acc[mi][0][r] + hb0;
      const float gf = acc[mi][1][r] + hb1;
      const float gg = acc[mi][2][r] + hb2;
      const float go = acc[mi][3][r] + hb3;
      const float cn = fsigm(gf) * c0v + fsigm(gi) * ftanh(gg);
      hnew[m * 512 + hcol] = (__bf16)(fsigm(go) * ftanh(cn));
    }
  }
}

// --------------------------- GEMM2 + bias -----------------------------------
// A = hnew [65536 x 512], B = fwbff fragment-ordered [40 ns x 16 kc x 1KB].
// grid 1280 = 256 m-tiles x 5 n-tiles.
__global__ __launch_bounds__(512, 4) void gemm2_kernel(
    const __bf16* __restrict__ hnew, const __bf16* __restrict__ fcwf,
    const float* __restrict__ fcb, float* __restrict__ out) {
  const int t = threadIdx.x, wid = t >> 6, l = t & 63;
  const int wm = wid >> 1, wc = wid & 1;
  const int bid = blockIdx.x;
  const int swz = (bid & 7) * 160 + (bid >> 3);
  const size_t m0 = (size_t)(swz / 5) << 8;
  const int n0 = (swz % 5) << 7;

  __shared__ __align__(16) char lds[49152];

  f32x4 acc[4][4];
#pragma unroll
  for (int mi = 0; mi < 4; ++mi)
#pragma unroll
    for (int ni = 0; ni < 4; ++ni) acc[mi][ni] = (f32x4){0.f, 0.f, 0.f, 0.f};

  gemm_core<16, 512, 16>(hnew, fcwf, m0, n0 >> 4, lds, acc, wid, l, wm, wc);

  const int lr = l & 15, lq = l >> 4;
#pragma unroll
  for (int ni = 0; ni < 4; ++ni) {
    const int n = n0 + wc * 64 + ni * 16 + lr;
    if (n < 513) {
      const float bias = fcb[n];
#pragma unroll
      for (int mi = 0; mi < 4; ++mi) {
#pragma unroll
        for (int r = 0; r < 4; ++r) {
          const size_t m = m0 + wm * 64 + mi * 16 + lq * 4 + r;
          out[m * 513 + n] = acc[mi][ni][r] + bias;
        }
      }
    }
  }
}

// --------------------------- launch -----------------------------------------
extern "C" void kernel_launch(void* const* d_in, const int* in_sizes, int n_in,
                              void* d_out, int out_size, void* d_ws, size_t ws_size,
                              hipStream_t stream) {
  const float* x = (const float*)d_in[0];     // [64,1024,513]
  const float* h0 = (const float*)d_in[1];    // [1,64,512]
  const float* c0 = (const float*)d_in[2];    // [1,64,512]
  const float* Wih = (const float*)d_in[3];   // [2048,513]
  const float* Whh = (const float*)d_in[4];   // [2048,512]
  const float* bih = (const float*)d_in[5];   // [2048]
  const float* bhh = (const float*)d_in[6];   // [2048]
  const float* fcw = (const float*)d_in[7];   // [513,512]
  const float* fcb = (const float*)d_in[8];   // [513]
  float* out = (float*)d_out;                 // [64,1024,513]

  char* ws = (char*)d_ws;
  __bf16* xbf = (__bf16*)(ws);                 // 65536*544*2 = 71,303,168
  __bf16* wpkf = (__bf16*)(ws + 71303168);     // 128*17*1024 =  2,228,224
  __bf16* fwbff = (__bf16*)(ws + 73531392);    //  40*16*1024 =    655,360
  float* hb = (float*)(ws + 74186752);         //   64*2048*4 =    524,288
  __bf16* hn = (__bf16*)(ws + 74711040);       // 65536*512*2 = 67,108,864
  // total ws use: 141,819,904 bytes

  pack_bf16_kernel<<<65536, 256, 0, stream>>>(x, xbf, 65536, 513, 544);
  pack_wfrag_kernel<<<2048, 128, 0, stream>>>(Wih, wpkf);
  pack_fcwfrag_kernel<<<640, 64, 0, stream>>>(fcw, fwbff);
  hbias_kernel<<<32768, 256, 0, stream>>>(h0, Whh, bih, bhh, hb);
  gemm1_kernel<<<4096, 512, 0, stream>>>(xbf, wpkf, hb, c0, hn);
  gemm2_kernel<<<1280, 512, 0, stream>>>(hn, fwbff, fcb, out);
}

// Round 12
// 410.918 us; speedup vs baseline: 1.2541x; 1.2541x over previous
//
#include <hip/hip_runtime.h>
#include <hip/hip_bf16.h>
#include <stdint.h>

// ---------------------------------------------------------------------------
// Decoder (teacher-forced, state never advances):
//   gates = x @ W_ih^T + (h0 @ W_hh^T + b_ih + b_hh)  (broadcast over t)
//   i,f,g,o = split(gates); c' = sig(f)*c0 + sig(i)*tanh(g); h' = sig(o)*tanh(c')
//   out = h' @ fc_w^T + fc_b
// Sizes: B=64, T=1024, D=513, H=512, 4H=2048.  M = B*T = 65536.
// R11: revert gemm1/gemm2 to R4 (best measured: 128x128 tile, 4 waves,
//     BK=32, triple-buffered 48KB LDS, 3 blocks/CU, one barrier + counted
//     vmcnt(4)/K-tile, fragment-ordered 0-conflict LDS, setprio, XCD swizzle,
//     gate-interleaved W). Reclaim auxiliary time:
//     - hbias: tiled GEMV (Whh rows + h0 chunks staged in LDS, k-split +
//       shuffle reduce, f32-exact). ~536 MB L2 traffic -> ~36 MB.
//     - pack_x: flat grid-stride chunks, vectorized 16B stores, 2048 blocks.
// ---------------------------------------------------------------------------

typedef __bf16 bf16x8 __attribute__((ext_vector_type(8)));
typedef float f32x4 __attribute__((ext_vector_type(4)));

#define MFMA_BF16 __builtin_amdgcn_mfma_f32_16x16x32_bf16

__device__ __forceinline__ void gld16(const void* gptr, void* lptr) {
  __builtin_amdgcn_global_load_lds(
      (const __attribute__((address_space(1))) void*)gptr,
      (__attribute__((address_space(3))) void*)lptr, 16, 0, 0);
}

__device__ __forceinline__ float fsigm(float x) {
  x = fminf(fmaxf(x, -30.f), 30.f);
  return __frcp_rn(1.f + __expf(-x));
}
__device__ __forceinline__ float ftanh(float x) {
  x = fminf(fmaxf(x, -15.f), 15.f);
  const float e = __expf(2.f * x);
  return (e - 1.f) * __frcp_rn(e + 1.f);
}

// --------------------------- pack x: f32[65536][513] -> bf16[65536][544] ----
// Flat over 8-element destination chunks (544/8 = 68 per row); grid-stride.
__global__ __launch_bounds__(256) void pack_x_kernel(
    const float* __restrict__ in, __bf16* __restrict__ out) {
  const unsigned total = 65536u * 68u;
  for (unsigned idx = blockIdx.x * 256 + threadIdx.x; idx < total;
       idx += 2048u * 256u) {
    const unsigned r = idx / 68u;
    const unsigned c = (idx % 68u) * 8u;
    const float* src = in + (size_t)r * 513 + c;
    union { __bf16 v[8]; uint4 u; } pk;
#pragma unroll
    for (int j = 0; j < 8; ++j)
      pk.v[j] = (__bf16)((c + j < 513) ? src[j] : 0.f);
    *(uint4*)(out + (size_t)r * 544 + c) = pk.u;
  }
}

// --------------------------- generic row pack (fcw) --------------------------
__global__ void pack_bf16_kernel(const float* __restrict__ in,
                                 __bf16* __restrict__ out,
                                 int rows_in, int kin, int kout) {
  const int r = blockIdx.x;
  const bool rv = r < rows_in;
  for (int c = threadIdx.x * 2; c < kout; c += 512) {
    float v0 = (rv && c < kin) ? in[(size_t)r * kin + c] : 0.f;
    float v1 = (rv && c + 1 < kin) ? in[(size_t)r * kin + c + 1] : 0.f;
    union { __bf16 h[2]; uint32_t u; } p;
    p.h[0] = (__bf16)v0;
    p.h[1] = (__bf16)v1;
    *(uint32_t*)&out[(size_t)r * kout + c] = p.u;
  }
}

// pack W_ih gate-interleaved: packed row p -> gate (p>>4)&3, h (p>>6)*16+(p&15)
__global__ void pack_wih_kernel(const float* __restrict__ Wih,
                                __bf16* __restrict__ wpk) {
  const int p = blockIdx.x;  // 0..2047
  const int g = (p >> 4) & 3;
  const int h = ((p >> 6) << 4) + (p & 15);
  const float* src = Wih + (size_t)(g * 512 + h) * 513;
  for (int c = threadIdx.x * 2; c < 544; c += 512) {
    float v0 = (c < 513) ? src[c] : 0.f;
    float v1 = (c + 1 < 513) ? src[c + 1] : 0.f;
    union { __bf16 hh[2]; uint32_t u; } pk;
    pk.hh[0] = (__bf16)v0;
    pk.hh[1] = (__bf16)v1;
    *(uint32_t*)&wpk[(size_t)p * 544 + c] = pk.u;
  }
}

// --------------------------- hbias (tiled GEMV, f32-exact) -------------------
// hbias[b][g] = dot(h0[b,:], W_hh[g,:]) + b_ih[g] + b_hh[g]
// grid 256 blocks x 256 thr; block owns 8 g. LDS: Whh rows 16KB + h0 chunk
// 32KB (16 b-rows), 4 chunks. Thread (g = t>>5, kg = t&31) accumulates over
// k = kg + 32*q (bank-conflict-free LDS reads), 32-lane shuffle reduce.
__global__ __launch_bounds__(256) void hbias_kernel(
    const float* __restrict__ h0, const float* __restrict__ Whh,
    const float* __restrict__ bih, const float* __restrict__ bhh,
    float* __restrict__ hbias) {
  __shared__ float wsm[8][512];
  __shared__ float hsm[16][512];
  const int t = threadIdx.x;
  const int g0 = blockIdx.x * 8;
  for (int i = t; i < 8 * 512; i += 256)
    wsm[i >> 9][i & 511] = Whh[(size_t)(g0 + (i >> 9)) * 512 + (i & 511)];
  const int g = t >> 5;   // 0..7
  const int kg = t & 31;  // 0..31
  const float bsum = bih[g0 + g] + bhh[g0 + g];
  for (int bc = 0; bc < 4; ++bc) {  // 16 b-rows per chunk
    __syncthreads();
    for (int i = t; i < 16 * 512; i += 256)
      hsm[i >> 9][i & 511] = h0[(size_t)(bc * 16 + (i >> 9)) * 512 + (i & 511)];
    __syncthreads();
#pragma unroll
    for (int bb = 0; bb < 16; ++bb) {
      float s = 0.f;
#pragma unroll
      for (int q = 0; q < 16; ++q)
        s = fmaf(hsm[bb][kg + 32 * q], wsm[g][kg + 32 * q], s);
#pragma unroll
      for (int off = 16; off; off >>= 1) s += __shfl_down(s, off, 32);
      if (kg == 0) hbias[(bc * 16 + bb) * 2048 + g0 + g] = s + bsum;
    }
  }
}

// --------------------------- triple-buffer GEMM core (R4) -------------------
// Tile 128x128, BK=32, 4 waves (2M x 2N), per-wave 64x64 (acc[4][4]).
// LDS: 3 buffers x (A 8KB + B 8KB) = 48KB. Tile kt reads buf kt%3 and stages
// tile kt+2 into (kt+2)%3 -> read/write buffers always disjoint; one barrier
// per tile; steady-state gate vmcnt(4) (waits only the tile-(kt+1) stage).
// Subtile = 16 rows x 32 k, fragment-ordered (lane l <-> row l&15, kq l>>4):
// gld16 dest and ds_read are both identity (base + l*16) -> 0 conflicts.
template <int NKT, int KSTR>
__device__ __forceinline__ void gemm_core(
    const __bf16* __restrict__ A, const __bf16* __restrict__ B,
    size_t m0, int n0, char* lds, f32x4 (&acc)[4][4],
    int w, int l, int wm, int wc) {
  const int lr = l & 15, lq = l >> 4;
  const __bf16* ag = A + (m0 + w * 32 + lr) * KSTR + lq * 8;
  const __bf16* bg = B + (size_t)(n0 + w * 32 + lr) * KSTR + lq * 8;
  const int sdst = w * 2048;            // wave-uniform LDS dest (2 subtiles)
  const int ra = wm * 4096 + l * 16;    // A read base, + mi*1024
  const int rbB = 8192 + wc * 4096 + l * 16;  // B read base, + ni*1024

  // prologue: stage K-tiles 0 and 1 into buffers 0 and 1
#pragma unroll
  for (int p = 0; p < 2; ++p) {
    char* base = lds + p * 16384;
    gld16(ag + p * 32, base + sdst);
    gld16(ag + p * 32 + 16 * KSTR, base + sdst + 1024);
    gld16(bg + p * 32, base + 8192 + sdst);
    gld16(bg + p * 32 + 16 * KSTR, base + 8192 + sdst + 1024);
  }
  asm volatile("s_waitcnt vmcnt(4)" ::: "memory");  // tile-0 stage landed
  __builtin_amdgcn_s_barrier();

  int rb = 0;
  for (int kt = 0; kt < NKT; ++kt) {
    char* rbase = lds + rb * 16384;
    if (kt + 2 < NKT) {  // stage tile kt+2 into the buffer freed at kt-1
      char* wbase = lds + ((rb + 2) % 3) * 16384;
      const int kof = (kt + 2) * 32;
      gld16(ag + kof, wbase + sdst);
      gld16(ag + kof + 16 * KSTR, wbase + sdst + 1024);
      gld16(bg + kof, wbase + 8192 + sdst);
      gld16(bg + kof + 16 * KSTR, wbase + 8192 + sdst + 1024);
    }
    bf16x8 af[4], bq[4];
#pragma unroll
    for (int i = 0; i < 4; ++i)
      af[i] = *(const bf16x8*)(rbase + ra + i * 1024);
#pragma unroll
    for (int i = 0; i < 4; ++i)
      bq[i] = *(const bf16x8*)(rbase + rbB + i * 1024);
    __builtin_amdgcn_s_setprio(1);
#pragma unroll
    for (int mi = 0; mi < 4; ++mi)
#pragma unroll
      for (int ni = 0; ni < 4; ++ni)
        acc[mi][ni] = MFMA_BF16(af[mi], bq[ni], acc[mi][ni], 0, 0, 0);
    __builtin_amdgcn_s_setprio(0);
    if (kt + 2 < NKT) {
      asm volatile("s_waitcnt vmcnt(4)" ::: "memory");  // tile kt+1 landed
    } else if (kt + 1 < NKT) {
      asm volatile("s_waitcnt vmcnt(0)" ::: "memory");  // tail: last tile
    }
    asm volatile("" ::: "memory");
    __builtin_amdgcn_s_barrier();
    rb = (rb == 2) ? 0 : rb + 1;
  }
}

// --------------------------- GEMM1 + LSTM cell ------------------------------
// A = xbf [65536 x 544], B = wpk [2048 x 544] gate-interleaved.
// grid 8192 = 512 m-tiles x 16 n-tiles.
__global__ __launch_bounds__(256, 3) void gemm1_kernel(
    const __bf16* __restrict__ xbf, const __bf16* __restrict__ wpk,
    const float* __restrict__ hbias, const float* __restrict__ c0,
    __bf16* __restrict__ hnew) {
  const int t = threadIdx.x, w = t >> 6, l = t & 63;
  const int wm = w >> 1, wc = w & 1;
  const int bid = blockIdx.x;
  const int swz = (bid & 7) * 1024 + (bid >> 3);  // XCD-contiguous
  const size_t m0 = (size_t)(swz >> 4) << 7;
  const int n0 = (swz & 15) << 7;

  __shared__ __align__(16) char lds[49152];

  f32x4 acc[4][4];
#pragma unroll
  for (int mi = 0; mi < 4; ++mi)
#pragma unroll
    for (int ni = 0; ni < 4; ++ni) acc[mi][ni] = (f32x4){0.f, 0.f, 0.f, 0.f};

  gemm_core<17, 544>(xbf, wpk, m0, n0, lds, acc, w, l, wm, wc);

  // lane's packed col p = n0 + wc*64 + ni*16 + (l&15) -> gate = ni,
  // h = (n0/64 + wc)*16 + (l&15). All 4 gates lane-local.
  const int lr = l & 15, lq = l >> 4;
  const int hcol = (((n0 >> 6) + wc) << 4) + lr;
  const int b = (int)(m0 >> 10);
  const float hb0 = hbias[b * 2048 + hcol];
  const float hb1 = hbias[b * 2048 + 512 + hcol];
  const float hb2 = hbias[b * 2048 + 1024 + hcol];
  const float hb3 = hbias[b * 2048 + 1536 + hcol];
  const float c0v = c0[b * 512 + hcol];
#pragma unroll
  for (int mi = 0; mi < 4; ++mi) {
#pragma unroll
    for (int r = 0; r < 4; ++r) {
      const size_t m = m0 + wm * 64 + mi * 16 + lq * 4 + r;
      const float gi = acc[mi][0][r] + hb0;
      const float gf = acc[mi][1][r] + hb1;
      const float gg = acc[mi][2][r] + hb2;
      const float go = acc[mi][3][r] + hb3;
      const float cn = fsigm(gf) * c0v + fsigm(gi) * ftanh(gg);
      hnew[m * 512 + hcol] = (__bf16)(fsigm(go) * ftanh(cn));
    }
  }
}

// --------------------------- GEMM2 + bias -----------------------------------
// A = hnew [65536 x 512], B = fwbf [640 x 512] (rows 513.. zero).
// grid 2560 = 512 m-tiles x 5 n-tiles.
__global__ __launch_bounds__(256, 3) void gemm2_kernel(
    const __bf16* __restrict__ hnew, const __bf16* __restrict__ fcw,
    const float* __restrict__ fcb, float* __restrict__ out) {
  const int t = threadIdx.x, w = t >> 6, l = t & 63;
  const int wm = w >> 1, wc = w & 1;
  const int bid = blockIdx.x;
  const int swz = (bid & 7) * 320 + (bid >> 3);
  const size_t m0 = (size_t)(swz / 5) << 7;
  const int n0 = (swz % 5) << 7;

  __shared__ __align__(16) char lds[49152];

  f32x4 acc[4][4];
#pragma unroll
  for (int mi = 0; mi < 4; ++mi)
#pragma unroll
    for (int ni = 0; ni < 4; ++ni) acc[mi][ni] = (f32x4){0.f, 0.f, 0.f, 0.f};

  gemm_core<16, 512>(hnew, fcw, m0, n0, lds, acc, w, l, wm, wc);

  const int lr = l & 15, lq = l >> 4;
#pragma unroll
  for (int ni = 0; ni < 4; ++ni) {
    const int n = n0 + wc * 64 + ni * 16 + lr;
    if (n < 513) {
      const float bias = fcb[n];
#pragma unroll
      for (int mi = 0; mi < 4; ++mi) {
#pragma unroll
        for (int r = 0; r < 4; ++r) {
          const size_t m = m0 + wm * 64 + mi * 16 + lq * 4 + r;
          out[m * 513 + n] = acc[mi][ni][r] + bias;
        }
      }
    }
  }
}

// --------------------------- launch -----------------------------------------
extern "C" void kernel_launch(void* const* d_in, const int* in_sizes, int n_in,
                              void* d_out, int out_size, void* d_ws, size_t ws_size,
                              hipStream_t stream) {
  const float* x = (const float*)d_in[0];     // [64,1024,513]
  const float* h0 = (const float*)d_in[1];    // [1,64,512]
  const float* c0 = (const float*)d_in[2];    // [1,64,512]
  const float* Wih = (const float*)d_in[3];   // [2048,513]
  const float* Whh = (const float*)d_in[4];   // [2048,512]
  const float* bih = (const float*)d_in[5];   // [2048]
  const float* bhh = (const float*)d_in[6];   // [2048]
  const float* fcw = (const float*)d_in[7];   // [513,512]
  const float* fcb = (const float*)d_in[8];   // [513]
  float* out = (float*)d_out;                 // [64,1024,513]

  char* ws = (char*)d_ws;
  __bf16* xbf = (__bf16*)(ws);                 // 65536*544*2 = 71,303,168
  __bf16* wpk = (__bf16*)(ws + 71303168);      //  2048*544*2 =  2,228,224
  __bf16* fwbf = (__bf16*)(ws + 73531392);     //   640*512*2 =    655,360
  float* hb = (float*)(ws + 74186752);         //   64*2048*4 =    524,288
  __bf16* hn = (__bf16*)(ws + 74711040);       // 65536*512*2 = 67,108,864
  // total ws use: 141,819,904 bytes

  pack_x_kernel<<<2048, 256, 0, stream>>>(x, xbf);
  pack_wih_kernel<<<2048, 256, 0, stream>>>(Wih, wpk);
  pack_bf16_kernel<<<640, 256, 0, stream>>>(fcw, fwbf, 513, 512, 512);
  hbias_kernel<<<256, 256, 0, stream>>>(h0, Whh, bih, bhh, hb);
  gemm1_kernel<<<8192, 256, 0, stream>>>(xbf, wpk, hb, c0, hn);
  gemm2_kernel<<<2560, 256, 0, stream>>>(hn, fwbf, fcb, out);
}

// Round 13
// 390.469 us; speedup vs baseline: 1.3198x; 1.0524x over previous
//
#include <hip/hip_runtime.h>
#include <hip/hip_bf16.h>
#include <stdint.h>

// ---------------------------------------------------------------------------
// Decoder (teacher-forced, state never advances):
//   gates = x @ W_ih^T + (h0 @ W_hh^T + b_ih + b_hh)  (broadcast over t)
//   i,f,g,o = split(gates); c' = sig(f)*c0 + sig(i)*tanh(g); h' = sig(o)*tanh(c')
//   out = h' @ fc_w^T + fc_b
// Sizes: B=64, T=1024, D=513, H=512, 4H=2048.  M = B*T = 65536.
// R12: best-known assembly (no new structures):
//   - gemm1 = R4 kernel: 128x128, 4 waves, BK=32, 3x16KB LDS, 3 blocks/CU,
//     counted vmcnt(4), fragment-ordered 0-conflict LDS. Best: 210.3 us.
//   - gemm2 = R7 kernel: 256x128, 8 waves, BK=32, 3x24KB LDS, 2 blocks/CU,
//     counted vmcnt(3). From the best-total (381.7 us) run.
//   - aux (pack_x / pack_wih / pack_fcw / hbias) = R7-era proven versions
//     (aux total ~165 us; R11's "improvements" cost +23 -> reverted).
// ---------------------------------------------------------------------------

typedef __bf16 bf16x8 __attribute__((ext_vector_type(8)));
typedef float f32x4 __attribute__((ext_vector_type(4)));

#define MFMA_BF16 __builtin_amdgcn_mfma_f32_16x16x32_bf16

__device__ __forceinline__ void gld16(const void* gptr, void* lptr) {
  __builtin_amdgcn_global_load_lds(
      (const __attribute__((address_space(1))) void*)gptr,
      (__attribute__((address_space(3))) void*)lptr, 16, 0, 0);
}

__device__ __forceinline__ float fsigm(float x) {
  x = fminf(fmaxf(x, -30.f), 30.f);
  return __frcp_rn(1.f + __expf(-x));
}
__device__ __forceinline__ float ftanh(float x) {
  x = fminf(fmaxf(x, -15.f), 15.f);
  const float e = __expf(2.f * x);
  return (e - 1.f) * __frcp_rn(e + 1.f);
}

// --------------------------- pack fp32 -> bf16 ------------------------------
__global__ void pack_bf16_kernel(const float* __restrict__ in,
                                 __bf16* __restrict__ out,
                                 int rows_in, int kin, int kout) {
  const int r = blockIdx.x;
  const bool rv = r < rows_in;
  for (int c = threadIdx.x * 2; c < kout; c += 512) {
    float v0 = (rv && c < kin) ? in[(size_t)r * kin + c] : 0.f;
    float v1 = (rv && c + 1 < kin) ? in[(size_t)r * kin + c + 1] : 0.f;
    union { __bf16 h[2]; uint32_t u; } p;
    p.h[0] = (__bf16)v0;
    p.h[1] = (__bf16)v1;
    *(uint32_t*)&out[(size_t)r * kout + c] = p.u;
  }
}

// pack W_ih gate-interleaved: packed row p -> gate (p>>4)&3, h (p>>6)*16+(p&15)
__global__ void pack_wih_kernel(const float* __restrict__ Wih,
                                __bf16* __restrict__ wpk) {
  const int p = blockIdx.x;  // 0..2047
  const int g = (p >> 4) & 3;
  const int h = ((p >> 6) << 4) + (p & 15);
  const float* src = Wih + (size_t)(g * 512 + h) * 513;
  for (int c = threadIdx.x * 2; c < 544; c += 512) {
    float v0 = (c < 513) ? src[c] : 0.f;
    float v1 = (c + 1 < 513) ? src[c + 1] : 0.f;
    union { __bf16 hh[2]; uint32_t u; } pk;
    pk.hh[0] = (__bf16)v0;
    pk.hh[1] = (__bf16)v1;
    *(uint32_t*)&wpk[(size_t)p * 544 + c] = pk.u;
  }
}

// --------------------------- hbias (R7-era proven) ---------------------------
__global__ void hbias_kernel(const float* __restrict__ h0,
                             const float* __restrict__ Whh,
                             const float* __restrict__ bih,
                             const float* __restrict__ bhh,
                             float* __restrict__ hbias) {
  const int t = threadIdx.x, w = t >> 6, l = t & 63;
  const int b = blockIdx.x >> 9;
  const int g = ((blockIdx.x & 511) << 2) | w;
  const float* hr = h0 + b * 512;
  const float* wr = Whh + (size_t)g * 512;
  float s = 0.f;
#pragma unroll
  for (int h = 0; h < 512; h += 64) s = fmaf(hr[h + l], wr[h + l], s);
#pragma unroll
  for (int off = 32; off; off >>= 1) s += __shfl_down(s, off);
  if (l == 0) hbias[b * 2048 + g] = s + bih[g] + bhh[g];
}

// --------------------------- R4 core: 128x128, 4 waves ----------------------
// LDS: 3 buffers x (A 8KB + B 8KB) = 48KB. One barrier + vmcnt(4)/K-tile.
// Subtile 16x32 fragment-ordered: gld16 dest and ds_read both identity.
template <int NKT, int KSTR>
__device__ __forceinline__ void gemm_core4(
    const __bf16* __restrict__ A, const __bf16* __restrict__ B,
    size_t m0, int n0, char* lds, f32x4 (&acc)[4][4],
    int w, int l, int wm, int wc) {
  const int lr = l & 15, lq = l >> 4;
  const __bf16* ag = A + (m0 + w * 32 + lr) * KSTR + lq * 8;
  const __bf16* bg = B + (size_t)(n0 + w * 32 + lr) * KSTR + lq * 8;
  const int sdst = w * 2048;
  const int ra = wm * 4096 + l * 16;
  const int rbB = 8192 + wc * 4096 + l * 16;

#pragma unroll
  for (int p = 0; p < 2; ++p) {
    char* base = lds + p * 16384;
    gld16(ag + p * 32, base + sdst);
    gld16(ag + p * 32 + 16 * KSTR, base + sdst + 1024);
    gld16(bg + p * 32, base + 8192 + sdst);
    gld16(bg + p * 32 + 16 * KSTR, base + 8192 + sdst + 1024);
  }
  asm volatile("s_waitcnt vmcnt(4)" ::: "memory");
  __builtin_amdgcn_s_barrier();

  int rb = 0;
  for (int kt = 0; kt < NKT; ++kt) {
    char* rbase = lds + rb * 16384;
    if (kt + 2 < NKT) {
      char* wbase = lds + ((rb + 2) % 3) * 16384;
      const int kof = (kt + 2) * 32;
      gld16(ag + kof, wbase + sdst);
      gld16(ag + kof + 16 * KSTR, wbase + sdst + 1024);
      gld16(bg + kof, wbase + 8192 + sdst);
      gld16(bg + kof + 16 * KSTR, wbase + 8192 + sdst + 1024);
    }
    bf16x8 af[4], bq[4];
#pragma unroll
    for (int i = 0; i < 4; ++i)
      af[i] = *(const bf16x8*)(rbase + ra + i * 1024);
#pragma unroll
    for (int i = 0; i < 4; ++i)
      bq[i] = *(const bf16x8*)(rbase + rbB + i * 1024);
    __builtin_amdgcn_s_setprio(1);
#pragma unroll
    for (int mi = 0; mi < 4; ++mi)
#pragma unroll
      for (int ni = 0; ni < 4; ++ni)
        acc[mi][ni] = MFMA_BF16(af[mi], bq[ni], acc[mi][ni], 0, 0, 0);
    __builtin_amdgcn_s_setprio(0);
    if (kt + 2 < NKT) {
      asm volatile("s_waitcnt vmcnt(4)" ::: "memory");
    } else if (kt + 1 < NKT) {
      asm volatile("s_waitcnt vmcnt(0)" ::: "memory");
    }
    asm volatile("" ::: "memory");
    __builtin_amdgcn_s_barrier();
    rb = (rb == 2) ? 0 : rb + 1;
  }
}

// --------------------------- R7 core: 256x128, 8 waves ----------------------
// LDS: 3 buffers x (A 16KB + B 8KB) = 72KB. One barrier + vmcnt(3)/K-tile.
// A: wave wid stages subtiles {wid, wid+8}; B: wave wid stages subtile wid.
template <int NKT, int KSTR>
__device__ __forceinline__ void gemm_core8(
    const __bf16* __restrict__ A, const __bf16* __restrict__ B,
    size_t m0, int n0, char* lds, f32x4 (&acc)[4][4],
    int wid, int l, int wm, int wc) {
  const int lr = l & 15, lq = l >> 4;
  const __bf16* ag = A + (m0 + wid * 16 + lr) * KSTR + lq * 8;
  const __bf16* ag2 = ag + (size_t)128 * KSTR;
  const __bf16* bg = B + (size_t)(n0 + wid * 16 + lr) * KSTR + lq * 8;
  const int sdA = wid << 10;
  const int sdB = 16384 + (wid << 10);
  const int ra = (wm << 12) + l * 16;
  const int rbB = 16384 + (wc << 12) + l * 16;

#pragma unroll
  for (int p = 0; p < 2; ++p) {
    char* base = lds + p * 24576;
    gld16(ag + p * 32, base + sdA);
    gld16(ag2 + p * 32, base + sdA + 8192);
    gld16(bg + p * 32, base + sdB);
  }
  asm volatile("s_waitcnt vmcnt(3)" ::: "memory");
  __builtin_amdgcn_s_barrier();

#pragma unroll
  for (int kt = 0; kt < NKT; ++kt) {
    char* rbase = lds + (kt % 3) * 24576;
    if (kt + 2 < NKT) {
      char* wbase = lds + ((kt + 2) % 3) * 24576;
      const int kof = (kt + 2) * 32;
      gld16(ag + kof, wbase + sdA);
      gld16(ag2 + kof, wbase + sdA + 8192);
      gld16(bg + kof, wbase + sdB);
    }
    bf16x8 af[4], bq[4];
#pragma unroll
    for (int i = 0; i < 4; ++i)
      af[i] = *(const bf16x8*)(rbase + ra + i * 1024);
#pragma unroll
    for (int i = 0; i < 4; ++i)
      bq[i] = *(const bf16x8*)(rbase + rbB + i * 1024);
    __builtin_amdgcn_s_setprio(1);
#pragma unroll
    for (int mi = 0; mi < 4; ++mi)
#pragma unroll
      for (int ni = 0; ni < 4; ++ni)
        acc[mi][ni] = MFMA_BF16(af[mi], bq[ni], acc[mi][ni], 0, 0, 0);
    __builtin_amdgcn_s_setprio(0);
    if (kt + 2 < NKT) {
      asm volatile("s_waitcnt vmcnt(3)" ::: "memory");
    } else if (kt + 1 < NKT) {
      asm volatile("s_waitcnt vmcnt(0)" ::: "memory");
    }
    asm volatile("" ::: "memory");
    __builtin_amdgcn_s_barrier();
  }
}

// --------------------------- GEMM1 + LSTM cell (R4) -------------------------
// A = xbf [65536 x 544], B = wpk [2048 x 544] gate-interleaved.
// grid 8192 = 512 m-tiles x 16 n-tiles.
__global__ __launch_bounds__(256, 3) void gemm1_kernel(
    const __bf16* __restrict__ xbf, const __bf16* __restrict__ wpk,
    const float* __restrict__ hbias, const float* __restrict__ c0,
    __bf16* __restrict__ hnew) {
  const int t = threadIdx.x, w = t >> 6, l = t & 63;
  const int wm = w >> 1, wc = w & 1;
  const int bid = blockIdx.x;
  const int swz = (bid & 7) * 1024 + (bid >> 3);  // XCD-contiguous
  const size_t m0 = (size_t)(swz >> 4) << 7;
  const int n0 = (swz & 15) << 7;

  __shared__ __align__(16) char lds[49152];

  f32x4 acc[4][4];
#pragma unroll
  for (int mi = 0; mi < 4; ++mi)
#pragma unroll
    for (int ni = 0; ni < 4; ++ni) acc[mi][ni] = (f32x4){0.f, 0.f, 0.f, 0.f};

  gemm_core4<17, 544>(xbf, wpk, m0, n0, lds, acc, w, l, wm, wc);

  // lane's packed col p = n0 + wc*64 + ni*16 + (l&15) -> gate = ni,
  // h = (n0/64 + wc)*16 + (l&15). All 4 gates lane-local.
  const int lr = l & 15, lq = l >> 4;
  const int hcol = (((n0 >> 6) + wc) << 4) + lr;
  const int b = (int)(m0 >> 10);
  const float hb0 = hbias[b * 2048 + hcol];
  const float hb1 = hbias[b * 2048 + 512 + hcol];
  const float hb2 = hbias[b * 2048 + 1024 + hcol];
  const float hb3 = hbias[b * 2048 + 1536 + hcol];
  const float c0v = c0[b * 512 + hcol];
#pragma unroll
  for (int mi = 0; mi < 4; ++mi) {
#pragma unroll
    for (int r = 0; r < 4; ++r) {
      const size_t m = m0 + wm * 64 + mi * 16 + lq * 4 + r;
      const float gi = acc[mi][0][r] + hb0;
      const float gf = acc[mi][1][r] + hb1;
      const float gg = acc[mi][2][r] + hb2;
      const float go = acc[mi][3][r] + hb3;
      const float cn = fsigm(gf) * c0v + fsigm(gi) * ftanh(gg);
      hnew[m * 512 + hcol] = (__bf16)(fsigm(go) * ftanh(cn));
    }
  }
}

// --------------------------- GEMM2 + bias (R7) ------------------------------
// A = hnew [65536 x 512], B = fwbf [640 x 512] (rows 513.. zero).
// grid 1280 = 256 m-tiles x 5 n-tiles.
__global__ __launch_bounds__(512, 4) void gemm2_kernel(
    const __bf16* __restrict__ hnew, const __bf16* __restrict__ fcw,
    const float* __restrict__ fcb, float* __restrict__ out) {
  const int t = threadIdx.x, wid = t >> 6, l = t & 63;
  const int wm = wid >> 1, wc = wid & 1;
  const int bid = blockIdx.x;
  const int swz = (bid & 7) * 160 + (bid >> 3);
  const size_t m0 = (size_t)(swz / 5) << 8;
  const int n0 = (swz % 5) << 7;

  __shared__ __align__(16) char lds[73728];

  f32x4 acc[4][4];
#pragma unroll
  for (int mi = 0; mi < 4; ++mi)
#pragma unroll
    for (int ni = 0; ni < 4; ++ni) acc[mi][ni] = (f32x4){0.f, 0.f, 0.f, 0.f};

  gemm_core8<16, 512>(hnew, fcw, m0, n0, lds, acc, wid, l, wm, wc);

  const int lr = l & 15, lq = l >> 4;
#pragma unroll
  for (int ni = 0; ni < 4; ++ni) {
    const int n = n0 + wc * 64 + ni * 16 + lr;
    if (n < 513) {
      const float bias = fcb[n];
#pragma unroll
      for (int mi = 0; mi < 4; ++mi) {
#pragma unroll
        for (int r = 0; r < 4; ++r) {
          const size_t m = m0 + wm * 64 + mi * 16 + lq * 4 + r;
          out[m * 513 + n] = acc[mi][ni][r] + bias;
        }
      }
    }
  }
}

// --------------------------- launch -----------------------------------------
extern "C" void kernel_launch(void* const* d_in, const int* in_sizes, int n_in,
                              void* d_out, int out_size, void* d_ws, size_t ws_size,
                              hipStream_t stream) {
  const float* x = (const float*)d_in[0];     // [64,1024,513]
  const float* h0 = (const float*)d_in[1];    // [1,64,512]
  const float* c0 = (const float*)d_in[2];    // [1,64,512]
  const float* Wih = (const float*)d_in[3];   // [2048,513]
  const float* Whh = (const float*)d_in[4];   // [2048,512]
  const float* bih = (const float*)d_in[5];   // [2048]
  const float* bhh = (const float*)d_in[6];   // [2048]
  const float* fcw = (const float*)d_in[7];   // [513,512]
  const float* fcb = (const float*)d_in[8];   // [513]
  float* out = (float*)d_out;                 // [64,1024,513]

  char* ws = (char*)d_ws;
  __bf16* xbf = (__bf16*)(ws);                 // 65536*544*2 = 71,303,168
  __bf16* wpk = (__bf16*)(ws + 71303168);      //  2048*544*2 =  2,228,224
  __bf16* fwbf = (__bf16*)(ws + 73531392);     //   640*512*2 =    655,360
  float* hb = (float*)(ws + 74186752);         //   64*2048*4 =    524,288
  __bf16* hn = (__bf16*)(ws + 74711040);       // 65536*512*2 = 67,108,864
  // total ws use: 141,819,904 bytes

  pack_bf16_kernel<<<65536, 256, 0, stream>>>(x, xbf, 65536, 513, 544);
  pack_wih_kernel<<<2048, 256, 0, stream>>>(Wih, wpk);
  pack_bf16_kernel<<<640, 256, 0, stream>>>(fcw, fwbf, 513, 512, 512);
  hbias_kernel<<<32768, 256, 0, stream>>>(h0, Whh, bih, bhh, hb);
  gemm1_kernel<<<8192, 256, 0, stream>>>(xbf, wpk, hb, c0, hn);
  gemm2_kernel<<<1280, 512, 0, stream>>>(hn, fwbf, fcb, out);
}

// Round 14
// 378.385 us; speedup vs baseline: 1.3620x; 1.0319x over previous
//
#include <hip/hip_runtime.h>
#include <hip/hip_bf16.h>
#include <stdint.h>

// ---------------------------------------------------------------------------
// Decoder (teacher-forced, state never advances):
//   gates = x @ W_ih^T + (h0 @ W_hh^T + b_ih + b_hh)  (broadcast over t)
//   i,f,g,o = split(gates); c' = sig(f)*c0 + sig(i)*tanh(g); h' = sig(o)*tanh(c')
//   out = h' @ fc_w^T + fc_b
// Sizes: B=64, T=1024, D=513, H=512, 4H=2048.  M = B*T = 65536.
// R13: fuse ALL prep (pack_x / pack_wih / pack_fcw / hbias) into ONE
//     role-split kernel (roles by blockIdx range, small roles dispatched
//     FIRST so they overlap pack_x's memory-bound tail). Role bodies are
//     byte-identical to R12's kernels -> the only delta is fusion+ordering.
//     gemm1 = R4 core (best measured), gemm2 = R7 core (best measured).
// ---------------------------------------------------------------------------

typedef __bf16 bf16x8 __attribute__((ext_vector_type(8)));
typedef float f32x4 __attribute__((ext_vector_type(4)));

#define MFMA_BF16 __builtin_amdgcn_mfma_f32_16x16x32_bf16

__device__ __forceinline__ void gld16(const void* gptr, void* lptr) {
  __builtin_amdgcn_global_load_lds(
      (const __attribute__((address_space(1))) void*)gptr,
      (__attribute__((address_space(3))) void*)lptr, 16, 0, 0);
}

__device__ __forceinline__ float fsigm(float x) {
  x = fminf(fmaxf(x, -30.f), 30.f);
  return __frcp_rn(1.f + __expf(-x));
}
__device__ __forceinline__ float ftanh(float x) {
  x = fminf(fmaxf(x, -15.f), 15.f);
  const float e = __expf(2.f * x);
  return (e - 1.f) * __frcp_rn(e + 1.f);
}

// --------------------------- fused prep -------------------------------------
// Roles by blockIdx.x (small roles first so they overlap pack_x):
//   [0, 2048)           pack_wih: 1 packed row each (gate-interleaved, K 544)
//   [2048, 2688)        pack_fcw: 1 row each (640 rows, K 512, >=513 zero)
//   [2688, 35456)       hbias: (b,g) GEMV, 4 waves = 4 g of one b
//   [35456, 100992)     pack_x: 1 row each (K 513 -> 544)
__global__ __launch_bounds__(256) void prep_kernel(
    const float* __restrict__ x, const float* __restrict__ Wih,
    const float* __restrict__ fcw, const float* __restrict__ h0,
    const float* __restrict__ Whh, const float* __restrict__ bih,
    const float* __restrict__ bhh, __bf16* __restrict__ xbf,
    __bf16* __restrict__ wpk, __bf16* __restrict__ fwbf,
    float* __restrict__ hbias) {
  const int bid = blockIdx.x;
  const int t = threadIdx.x;

  if (bid < 2048) {  // ---- pack_wih (R12 logic, 1 packed row per block)
    const int p = bid;
    const int g = (p >> 4) & 3;
    const int h = ((p >> 6) << 4) + (p & 15);
    const float* src = Wih + (size_t)(g * 512 + h) * 513;
    for (int c = t * 2; c < 544; c += 512) {
      float v0 = (c < 513) ? src[c] : 0.f;
      float v1 = (c + 1 < 513) ? src[c + 1] : 0.f;
      union { __bf16 hh[2]; uint32_t u; } pk;
      pk.hh[0] = (__bf16)v0;
      pk.hh[1] = (__bf16)v1;
      *(uint32_t*)&wpk[(size_t)p * 544 + c] = pk.u;
    }
  } else if (bid < 2688) {  // ---- pack_fcw (rows 0..639, K 512)
    const int r = bid - 2048;
    const bool rv = r < 513;
    const float* src = fcw + (size_t)r * 512;
    for (int c = t * 2; c < 512; c += 512) {
      float v0 = rv ? src[c] : 0.f;
      float v1 = rv ? src[c + 1] : 0.f;
      union { __bf16 hh[2]; uint32_t u; } pk;
      pk.hh[0] = (__bf16)v0;
      pk.hh[1] = (__bf16)v1;
      *(uint32_t*)&fwbf[(size_t)r * 512 + c] = pk.u;
    }
  } else if (bid < 35456) {  // ---- hbias (R12 logic)
    const int hb_bid = bid - 2688;
    const int w = t >> 6, l = t & 63;
    const int b = hb_bid >> 9;
    const int g = ((hb_bid & 511) << 2) | w;
    const float* hr = h0 + b * 512;
    const float* wr = Whh + (size_t)g * 512;
    float s = 0.f;
#pragma unroll
    for (int h = 0; h < 512; h += 64) s = fmaf(hr[h + l], wr[h + l], s);
#pragma unroll
    for (int off = 32; off; off >>= 1) s += __shfl_down(s, off);
    if (l == 0) hbias[b * 2048 + g] = s + bih[g] + bhh[g];
  } else {  // ---- pack_x (R12 logic, 1 row per block)
    const int r = bid - 35456;
    const float* src = x + (size_t)r * 513;
    for (int c = t * 2; c < 544; c += 512) {
      float v0 = (c < 513) ? src[c] : 0.f;
      float v1 = (c + 1 < 513) ? src[c + 1] : 0.f;
      union { __bf16 hh[2]; uint32_t u; } pk;
      pk.hh[0] = (__bf16)v0;
      pk.hh[1] = (__bf16)v1;
      *(uint32_t*)&xbf[(size_t)r * 544 + c] = pk.u;
    }
  }
}

// --------------------------- R4 core: 128x128, 4 waves ----------------------
// LDS: 3 buffers x (A 8KB + B 8KB) = 48KB. One barrier + vmcnt(4)/K-tile.
// Subtile 16x32 fragment-ordered: gld16 dest and ds_read both identity.
template <int NKT, int KSTR>
__device__ __forceinline__ void gemm_core4(
    const __bf16* __restrict__ A, const __bf16* __restrict__ B,
    size_t m0, int n0, char* lds, f32x4 (&acc)[4][4],
    int w, int l, int wm, int wc) {
  const int lr = l & 15, lq = l >> 4;
  const __bf16* ag = A + (m0 + w * 32 + lr) * KSTR + lq * 8;
  const __bf16* bg = B + (size_t)(n0 + w * 32 + lr) * KSTR + lq * 8;
  const int sdst = w * 2048;
  const int ra = wm * 4096 + l * 16;
  const int rbB = 8192 + wc * 4096 + l * 16;

#pragma unroll
  for (int p = 0; p < 2; ++p) {
    char* base = lds + p * 16384;
    gld16(ag + p * 32, base + sdst);
    gld16(ag + p * 32 + 16 * KSTR, base + sdst + 1024);
    gld16(bg + p * 32, base + 8192 + sdst);
    gld16(bg + p * 32 + 16 * KSTR, base + 8192 + sdst + 1024);
  }
  asm volatile("s_waitcnt vmcnt(4)" ::: "memory");
  __builtin_amdgcn_s_barrier();

  int rb = 0;
  for (int kt = 0; kt < NKT; ++kt) {
    char* rbase = lds + rb * 16384;
    if (kt + 2 < NKT) {
      char* wbase = lds + ((rb + 2) % 3) * 16384;
      const int kof = (kt + 2) * 32;
      gld16(ag + kof, wbase + sdst);
      gld16(ag + kof + 16 * KSTR, wbase + sdst + 1024);
      gld16(bg + kof, wbase + 8192 + sdst);
      gld16(bg + kof + 16 * KSTR, wbase + 8192 + sdst + 1024);
    }
    bf16x8 af[4], bq[4];
#pragma unroll
    for (int i = 0; i < 4; ++i)
      af[i] = *(const bf16x8*)(rbase + ra + i * 1024);
#pragma unroll
    for (int i = 0; i < 4; ++i)
      bq[i] = *(const bf16x8*)(rbase + rbB + i * 1024);
    __builtin_amdgcn_s_setprio(1);
#pragma unroll
    for (int mi = 0; mi < 4; ++mi)
#pragma unroll
      for (int ni = 0; ni < 4; ++ni)
        acc[mi][ni] = MFMA_BF16(af[mi], bq[ni], acc[mi][ni], 0, 0, 0);
    __builtin_amdgcn_s_setprio(0);
    if (kt + 2 < NKT) {
      asm volatile("s_waitcnt vmcnt(4)" ::: "memory");
    } else if (kt + 1 < NKT) {
      asm volatile("s_waitcnt vmcnt(0)" ::: "memory");
    }
    asm volatile("" ::: "memory");
    __builtin_amdgcn_s_barrier();
    rb = (rb == 2) ? 0 : rb + 1;
  }
}

// --------------------------- R7 core: 256x128, 8 waves ----------------------
// LDS: 3 buffers x (A 16KB + B 8KB) = 72KB. One barrier + vmcnt(3)/K-tile.
template <int NKT, int KSTR>
__device__ __forceinline__ void gemm_core8(
    const __bf16* __restrict__ A, const __bf16* __restrict__ B,
    size_t m0, int n0, char* lds, f32x4 (&acc)[4][4],
    int wid, int l, int wm, int wc) {
  const int lr = l & 15, lq = l >> 4;
  const __bf16* ag = A + (m0 + wid * 16 + lr) * KSTR + lq * 8;
  const __bf16* ag2 = ag + (size_t)128 * KSTR;
  const __bf16* bg = B + (size_t)(n0 + wid * 16 + lr) * KSTR + lq * 8;
  const int sdA = wid << 10;
  const int sdB = 16384 + (wid << 10);
  const int ra = (wm << 12) + l * 16;
  const int rbB = 16384 + (wc << 12) + l * 16;

#pragma unroll
  for (int p = 0; p < 2; ++p) {
    char* base = lds + p * 24576;
    gld16(ag + p * 32, base + sdA);
    gld16(ag2 + p * 32, base + sdA + 8192);
    gld16(bg + p * 32, base + sdB);
  }
  asm volatile("s_waitcnt vmcnt(3)" ::: "memory");
  __builtin_amdgcn_s_barrier();

#pragma unroll
  for (int kt = 0; kt < NKT; ++kt) {
    char* rbase = lds + (kt % 3) * 24576;
    if (kt + 2 < NKT) {
      char* wbase = lds + ((kt + 2) % 3) * 24576;
      const int kof = (kt + 2) * 32;
      gld16(ag + kof, wbase + sdA);
      gld16(ag2 + kof, wbase + sdA + 8192);
      gld16(bg + kof, wbase + sdB);
    }
    bf16x8 af[4], bq[4];
#pragma unroll
    for (int i = 0; i < 4; ++i)
      af[i] = *(const bf16x8*)(rbase + ra + i * 1024);
#pragma unroll
    for (int i = 0; i < 4; ++i)
      bq[i] = *(const bf16x8*)(rbase + rbB + i * 1024);
    __builtin_amdgcn_s_setprio(1);
#pragma unroll
    for (int mi = 0; mi < 4; ++mi)
#pragma unroll
      for (int ni = 0; ni < 4; ++ni)
        acc[mi][ni] = MFMA_BF16(af[mi], bq[ni], acc[mi][ni], 0, 0, 0);
    __builtin_amdgcn_s_setprio(0);
    if (kt + 2 < NKT) {
      asm volatile("s_waitcnt vmcnt(3)" ::: "memory");
    } else if (kt + 1 < NKT) {
      asm volatile("s_waitcnt vmcnt(0)" ::: "memory");
    }
    asm volatile("" ::: "memory");
    __builtin_amdgcn_s_barrier();
  }
}

// --------------------------- GEMM1 + LSTM cell (R4) -------------------------
// A = xbf [65536 x 544], B = wpk [2048 x 544] gate-interleaved.
// grid 8192 = 512 m-tiles x 16 n-tiles.
__global__ __launch_bounds__(256, 3) void gemm1_kernel(
    const __bf16* __restrict__ xbf, const __bf16* __restrict__ wpk,
    const float* __restrict__ hbias, const float* __restrict__ c0,
    __bf16* __restrict__ hnew) {
  const int t = threadIdx.x, w = t >> 6, l = t & 63;
  const int wm = w >> 1, wc = w & 1;
  const int bid = blockIdx.x;
  const int swz = (bid & 7) * 1024 + (bid >> 3);  // XCD-contiguous
  const size_t m0 = (size_t)(swz >> 4) << 7;
  const int n0 = (swz & 15) << 7;

  __shared__ __align__(16) char lds[49152];

  f32x4 acc[4][4];
#pragma unroll
  for (int mi = 0; mi < 4; ++mi)
#pragma unroll
    for (int ni = 0; ni < 4; ++ni) acc[mi][ni] = (f32x4){0.f, 0.f, 0.f, 0.f};

  gemm_core4<17, 544>(xbf, wpk, m0, n0, lds, acc, w, l, wm, wc);

  // lane's packed col p = n0 + wc*64 + ni*16 + (l&15) -> gate = ni,
  // h = (n0/64 + wc)*16 + (l&15). All 4 gates lane-local.
  const int lr = l & 15, lq = l >> 4;
  const int hcol = (((n0 >> 6) + wc) << 4) + lr;
  const int b = (int)(m0 >> 10);
  const float hb0 = hbias[b * 2048 + hcol];
  const float hb1 = hbias[b * 2048 + 512 + hcol];
  const float hb2 = hbias[b * 2048 + 1024 + hcol];
  const float hb3 = hbias[b * 2048 + 1536 + hcol];
  const float c0v = c0[b * 512 + hcol];
#pragma unroll
  for (int mi = 0; mi < 4; ++mi) {
#pragma unroll
    for (int r = 0; r < 4; ++r) {
      const size_t m = m0 + wm * 64 + mi * 16 + lq * 4 + r;
      const float gi = acc[mi][0][r] + hb0;
      const float gf = acc[mi][1][r] + hb1;
      const float gg = acc[mi][2][r] + hb2;
      const float go = acc[mi][3][r] + hb3;
      const float cn = fsigm(gf) * c0v + fsigm(gi) * ftanh(gg);
      hnew[m * 512 + hcol] = (__bf16)(fsigm(go) * ftanh(cn));
    }
  }
}

// --------------------------- GEMM2 + bias (R7) ------------------------------
// A = hnew [65536 x 512], B = fwbf [640 x 512] (rows 513.. zero).
// grid 1280 = 256 m-tiles x 5 n-tiles.
__global__ __launch_bounds__(512, 4) void gemm2_kernel(
    const __bf16* __restrict__ hnew, const __bf16* __restrict__ fcw,
    const float* __restrict__ fcb, float* __restrict__ out) {
  const int t = threadIdx.x, wid = t >> 6, l = t & 63;
  const int wm = wid >> 1, wc = wid & 1;
  const int bid = blockIdx.x;
  const int swz = (bid & 7) * 160 + (bid >> 3);
  const size_t m0 = (size_t)(swz / 5) << 8;
  const int n0 = (swz % 5) << 7;

  __shared__ __align__(16) char lds[73728];

  f32x4 acc[4][4];
#pragma unroll
  for (int mi = 0; mi < 4; ++mi)
#pragma unroll
    for (int ni = 0; ni < 4; ++ni) acc[mi][ni] = (f32x4){0.f, 0.f, 0.f, 0.f};

  gemm_core8<16, 512>(hnew, fcw, m0, n0, lds, acc, wid, l, wm, wc);

  const int lr = l & 15, lq = l >> 4;
#pragma unroll
  for (int ni = 0; ni < 4; ++ni) {
    const int n = n0 + wc * 64 + ni * 16 + lr;
    if (n < 513) {
      const float bias = fcb[n];
#pragma unroll
      for (int mi = 0; mi < 4; ++mi) {
#pragma unroll
        for (int r = 0; r < 4; ++r) {
          const size_t m = m0 + wm * 64 + mi * 16 + lq * 4 + r;
          out[m * 513 + n] = acc[mi][ni][r] + bias;
        }
      }
    }
  }
}

// --------------------------- launch -----------------------------------------
extern "C" void kernel_launch(void* const* d_in, const int* in_sizes, int n_in,
                              void* d_out, int out_size, void* d_ws, size_t ws_size,
                              hipStream_t stream) {
  const float* x = (const float*)d_in[0];     // [64,1024,513]
  const float* h0 = (const float*)d_in[1];    // [1,64,512]
  const float* c0 = (const float*)d_in[2];    // [1,64,512]
  const float* Wih = (const float*)d_in[3];   // [2048,513]
  const float* Whh = (const float*)d_in[4];   // [2048,512]
  const float* bih = (const float*)d_in[5];   // [2048]
  const float* bhh = (const float*)d_in[6];   // [2048]
  const float* fcw = (const float*)d_in[7];   // [513,512]
  const float* fcb = (const float*)d_in[8];   // [513]
  float* out = (float*)d_out;                 // [64,1024,513]

  char* ws = (char*)d_ws;
  __bf16* xbf = (__bf16*)(ws);                 // 65536*544*2 = 71,303,168
  __bf16* wpk = (__bf16*)(ws + 71303168);      //  2048*544*2 =  2,228,224
  __bf16* fwbf = (__bf16*)(ws + 73531392);     //   640*512*2 =    655,360
  float* hb = (float*)(ws + 74186752);         //   64*2048*4 =    524,288
  __bf16* hn = (__bf16*)(ws + 74711040);       // 65536*512*2 = 67,108,864
  // total ws use: 141,819,904 bytes

  prep_kernel<<<100992, 256, 0, stream>>>(x, Wih, fcw, h0, Whh, bih, bhh,
                                          xbf, wpk, fwbf, hb);
  gemm1_kernel<<<8192, 256, 0, stream>>>(xbf, wpk, hb, c0, hn);
  gemm2_kernel<<<1280, 512, 0, stream>>>(hn, fwbf, fcb, out);
}